// Round 2
// baseline (229.481 us; speedup 1.0000x reference)
//
#include <hip/hip_runtime.h>
#include <math.h>

typedef short v4s __attribute__((ext_vector_type(4)));
typedef short v8s __attribute__((ext_vector_type(8)));
typedef float v4f __attribute__((ext_vector_type(4)));

#define L2E 1.4426950408889634f
#define INV_SCALE 0.08838834764831845f       // 1/sqrt(128)
#define SCL2 (INV_SCALE * L2E)               // folded scale for exp2

static __device__ __forceinline__ short f2bf(float x) {
    union { float f; unsigned u; } c; c.f = x;
    unsigned u = c.u;
    unsigned r = (u + 0x7fffu + ((u >> 16) & 1u)) >> 16;  // RNE
    return (short)r;
}

typedef __attribute__((address_space(3))) void lds_vt;
typedef __attribute__((address_space(1))) const void gl_vt;
static __device__ __forceinline__ void gload_lds16(const void* g, void* l) {
    __builtin_amdgcn_global_load_lds((gl_vt*)g, (lds_vt*)l, 16, 0, 0);
}

// ---- P0 fused: gemm+ELU role (x<512) | transpose/mask role (x>=512) -----
// gemm role: full 128-f output per 64 m rows; W staged in two k-halves in
// the same 33.8 KB LDS -> X rows read ONCE (nh halves merged, 2x less X
// traffic than the split-nh version). VaT written with per-row chunk-XOR
// swizzle (g^(d&7) inside each 64-kv group) for conflict-free b128 reads.
__global__ __launch_bounds__(256) void k_pre(const float* __restrict__ ctx,
                                             const float* __restrict__ qry,
                                             const float* __restrict__ Win,
                                             const float* __restrict__ Wmem,
                                             const int* __restrict__ qmask,
                                             short* __restrict__ Qa,
                                             short* __restrict__ Ka,
                                             short* __restrict__ VaT,
                                             float* __restrict__ maskadd,
                                             int* __restrict__ flags) {
    __shared__ __align__(16) char sbuf[128 * 132 * 2];   // 33792 B (union)
    int x = blockIdx.x;
    int tid = threadIdx.x;
    if (x < 512) {
        // ---------------- gemm role ----------------
        short* WtS = (short*)sbuf;                      // [128 f][132 k-pad]
        int msel = x & 255, isel = x >> 8;
        const float* X = isel ? qry : ctx;
        const float* W = isel ? Wmem : Win;
        short* Y = isel ? Ka : Qa;

        int w = tid >> 6, lane = tid & 63;
        int ln = lane & 15, qd = lane >> 4;
        int m0 = msel * 64 + w * 16;
        v4f zero = {0.f, 0.f, 0.f, 0.f};
        v4f o[8];
#pragma unroll
        for (int i = 0; i < 8; ++i) o[i] = zero;

#pragma unroll 1
        for (int kh = 0; kh < 2; ++kh) {
            if (kh) __syncthreads();                    // protect WtS reuse
            // stage W k-half: 128 f x 128 k = 16384 elems, 64/thread
#pragma unroll 8
            for (int i = 0; i < 64; ++i) {
                int id = i * 256 + tid;
                int k = id >> 7, fp = id & 127;
                WtS[fp * 132 + k] = f2bf(W[(kh * 128 + k) * 128 + fp]);
            }
            __syncthreads();
#pragma unroll
            for (int kk = 0; kk < 4; ++kk) {
                const float* xp = X + (size_t)(m0 + ln) * 256 + kh * 128 + kk * 32 + qd * 8;
                float4 x0 = *(const float4*)xp;
                float4 x1 = *(const float4*)(xp + 4);
                v8s a;
                a[0] = f2bf(x0.x); a[1] = f2bf(x0.y); a[2] = f2bf(x0.z); a[3] = f2bf(x0.w);
                a[4] = f2bf(x1.x); a[5] = f2bf(x1.y); a[6] = f2bf(x1.z); a[7] = f2bf(x1.w);
#pragma unroll
                for (int nt = 0; nt < 8; ++nt) {
                    v8s bfr = *(const v8s*)(WtS + (nt * 16 + ln) * 132 + kk * 32 + qd * 8);
                    o[nt] = __builtin_amdgcn_mfma_f32_16x16x32_bf16(a, bfr, o[nt], 0, 0, 0);
                }
            }
        }
#pragma unroll
        for (int nt = 0; nt < 8; ++nt) {
#pragma unroll
            for (int r = 0; r < 4; ++r) {
                float v = o[nt][r];
                v = v > 0.f ? v : 0.01f * (__expf(v) - 1.f);
                Y[(size_t)(m0 + qd * 4 + r) * 128 + nt * 16 + ln] = f2bf(v);
            }
        }
    } else {
        // ---------------- transpose role ----------------
        float (*tile)[65] = (float(*)[65])sbuf;         // 16640 B
        int t = x - 512;
        int q0 = (t & 31) * 64, d0 = ((t >> 5) & 3) * 64, b = t >> 7;
        int c = tid & 63;
        int r4 = tid >> 6;
#pragma unroll
        for (int i = 0; i < 16; ++i) {
            int r = r4 + i * 4;
            tile[r][c] = qry[(size_t)(b * 2048 + q0 + r) * 256 + d0 + c];
        }
        __syncthreads();
        int g = c >> 3, j = c & 7;
#pragma unroll
        for (int i = 0; i < 16; ++i) {
            int d = r4 + i * 4;                          // (d0+d)&7 == d&7
            int cs = ((g ^ (d & 7)) << 3) | j;           // chunk-XOR swizzle
            VaT[(size_t)(b * 256 + d0 + d) * 2048 + q0 + cs] = f2bf(tile[c][d]);
        }
        if (d0 == 0 && tid < 64) {
            int qq = b * 2048 + q0 + tid;
            maskadd[qq] = (qmask[qq] > 0) ? 0.f : -__builtin_inff();
        }
        if (t == 0) flags[tid] = 0;                      // 256 pair flags
    }
}

// ------------- flash attention: c=64 tiles, kv-split, inline combine ------
// Grid 512 (NSPLIT=2): 8 b x 32 c-tiles x 2 kv-halves, 2 blocks/CU.
// Per 64-kv step: K frags + mask prefetched 1 step ahead in regs; V staged
// wave-private (d-quarter) via async global_load_lds into a SINGLE 32 KB
// buffer (stage issued after PV reads + lgkmcnt drain -> no dbuf needed);
// P double-buffered (chunk-XOR swizzled) -> ONE raw s_barrier per step;
// counted s_waitcnt vmcnt(5) keeps this step's 13 VMEM ops in flight.
// kv-split combine: both halves write unnormalized partials; the SECOND
// block (device-scope ACQ_REL atomic) merges regs+other-partial -> out.
template<int NSPLIT, bool DIRECT>
__global__ __launch_bounds__(256, 2) void k_attn(const short* __restrict__ Qa,
                                                 const short* __restrict__ Ka,
                                                 const short* __restrict__ VaT,
                                                 const float* __restrict__ maskadd,
                                                 float* __restrict__ Opart,
                                                 float* __restrict__ lpart,
                                                 int* __restrict__ flags,
                                                 float* __restrict__ out) {
    __shared__ __align__(16) short VaS[256 * 64];       // 32 KB [d][64kv] swizzled
    __shared__ __align__(16) short PSb[2][64 * 64];     // 16 KB [buf][c][kv] swizzled
    __shared__ int who;

    const int STEPS = 32 / NSPLIT;
    int blk = blockIdx.x;
    int b = blk & 7;
    int t = blk >> 3;
    int c0 = (t & 31) * 64;
    int sp = t >> 5;
    int kv0 = sp * (2048 / NSPLIT);

    int tid = threadIdx.x;
    int w = tid >> 6, lane = tid & 63, ln = lane & 15, qd = lane >> 4;

    const short* qbase = Qa + (size_t)(b * 2048) * 128;
    const short* kbase = Ka + (size_t)(b * 2048 + kv0 + w * 16 + ln) * 128 + qd * 8;
    const short* vbase = VaT + (size_t)(b * 256) * 2048;
    const float* mbase = maskadd + b * 2048 + kv0 + w * 16 + qd * 4;

    // Q fragments for all 4 c-tiles (B-operand layout), resident
    v8s qf[4][4];
#pragma unroll
    for (int ct = 0; ct < 4; ++ct) {
        const short* qp = qbase + (size_t)(c0 + ct * 16 + ln) * 128 + qd * 8;
#pragma unroll
        for (int kk = 0; kk < 4; ++kk) qf[ct][kk] = *(const v8s*)(qp + kk * 32);
    }

    v4f zero = {0.f, 0.f, 0.f, 0.f};
    v4f o[4][4];                            // [ct][dt]
#pragma unroll
    for (int i = 0; i < 4; ++i)
#pragma unroll
        for (int j = 0; j < 4; ++j) o[i][j] = zero;
    float lacc[4] = {0.f, 0.f, 0.f, 0.f};

    // stage own d-quarter of V tile for kv window q0s (wave-private rows)
    auto stageV = [&](int q0s) {
        short* base = &VaS[0] + w * 4096;    // rows w*64..+63
#pragma unroll
        for (int j = 0; j < 8; ++j) {
            int U = (w * 8 + j) * 64 + lane; // 16B unit index
            int d = U >> 3, cc = U & 7;
            gload_lds16(vbase + (size_t)d * 2048 + q0s + cc * 8,
                        base + j * 512);
        }
    };

    // ---- prologue: K/mask FIRST (so compiler's pre-QK wait is vmcnt(8),
    // keeping the 8 stage ops in flight), then V stage for step 0 ----
    v8s kfA[4], kfB[4];
    float4 mkA, mkB;
#pragma unroll
    for (int kk = 0; kk < 4; ++kk) kfA[kk] = *(const v8s*)(kbase + kk * 32);
    mkA = *(const float4*)(mbase);
    stageV(kv0);

#define ATT_STEP(IT, KFC, MKC, KFN, MKN) do {                                  \
    int q0 = kv0 + (IT) * 64;                                                  \
    int pb = (IT) & 1;                                                         \
    int itn = ((IT) + 1) & (STEPS - 1);                                        \
    {   /* prefetch next step's K frags + mask into regs (5 VMEM) */           \
        const short* kp = kbase + (size_t)itn * 8192;                          \
        _Pragma("unroll")                                                      \
        for (int kk = 0; kk < 4; ++kk) KFN[kk] = *(const v8s*)(kp + kk * 32);  \
        MKN = *(const float4*)(mbase + itn * 64);                              \
    }                                                                          \
    short* PScur = &PSb[pb][0];                                                \
    int kvb = q0 + w * 16 + qd * 4;                                            \
    _Pragma("unroll")                                                          \
    for (int ct = 0; ct < 4; ++ct) {                                           \
        v4f s = zero;                                                          \
        _Pragma("unroll")                                                      \
        for (int kk = 0; kk < 4; ++kk)                                         \
            s = __builtin_amdgcn_mfma_f32_16x16x32_bf16(KFC[kk], qf[ct][kk],   \
                                                        s, 0, 0, 0);           \
        int cg = c0 + ct * 16 + ln;                                            \
        v4s pw;                                                                \
        float ls = 0.f;                                                        \
        _Pragma("unroll")                                                      \
        for (int r = 0; r < 4; ++r) {                                          \
            float v = s[r] * SCL2 + (&MKC.x)[r];                               \
            if (kvb + r == cg) v = -__builtin_inff();                          \
            float p = exp2f(v);                                                \
            ls += p;                                                           \
            pw[r] = f2bf(p);                                                   \
        }                                                                      \
        lacc[ct] += ls;                                                        \
        int hs = ((w * 2 + (qd >> 1)) ^ (ln & 7));                             \
        *(v4s*)(PScur + (ct * 16 + ln) * 64 + hs * 8 + (qd & 1) * 4) = pw;     \
    }                                                                          \
    asm volatile("s_waitcnt lgkmcnt(0)" ::: "memory");                         \
    __builtin_amdgcn_s_barrier();                                              \
    /* retire the stage for THIS step (8 oldest); keep K-next (5) flying */    \
    asm volatile("s_waitcnt vmcnt(5)" ::: "memory");                           \
    const short* vs = &VaS[0];                                                 \
    __builtin_amdgcn_s_setprio(1);                                             \
    _Pragma("unroll")                                                          \
    for (int kk2 = 0; kk2 < 2; ++kk2) {                                        \
        v8s pf[4], vf[4];                                                      \
        _Pragma("unroll")                                                      \
        for (int ct = 0; ct < 4; ++ct)                                         \
            pf[ct] = *(const v8s*)(PScur + (ct * 16 + ln) * 64 +               \
                                   (((kk2 * 4 + qd) ^ (ln & 7)) << 3));        \
        _Pragma("unroll")                                                      \
        for (int dt = 0; dt < 4; ++dt) {                                       \
            int d = w * 64 + dt * 16 + ln;                                     \
            vf[dt] = *(const v8s*)(vs + d * 64 +                               \
                                   (((kk2 * 4 + qd) ^ (ln & 7)) << 3));        \
        }                                                                      \
        _Pragma("unroll")                                                      \
        for (int ct = 0; ct < 4; ++ct)                                         \
            _Pragma("unroll")                                                  \
            for (int dt = 0; dt < 4; ++dt)                                     \
                o[ct][dt] = __builtin_amdgcn_mfma_f32_16x16x32_bf16(           \
                    pf[ct], vf[dt], o[ct][dt], 0, 0, 0);                       \
    }                                                                          \
    __builtin_amdgcn_s_setprio(0);                                             \
    /* vf reads fully consumed -> safe to overwrite single V buffer */         \
    asm volatile("s_waitcnt lgkmcnt(0)" ::: "memory");                         \
    stageV(kv0 + itn * 64);                                                    \
} while (0)

#pragma unroll 1
    for (int it2 = 0; it2 < STEPS; it2 += 2) {
        ATT_STEP(it2, kfA, mkA, kfB, mkB);
        ATT_STEP(it2 + 1, kfB, mkB, kfA, mkA);
    }
#undef ATT_STEP

    // ---- l: reduce over qd in-wave, over waves via LDS (PS space reused) --
    __syncthreads();
    float* lS = (float*)&PSb[0][0];
#pragma unroll
    for (int ct = 0; ct < 4; ++ct) {
        float v = lacc[ct];
        v += __shfl_xor(v, 16);
        v += __shfl_xor(v, 32);
        if (qd == 0) lS[w * 64 + ct * 16 + ln] = v;
    }
    __syncthreads();

    float flv[4][4];
#pragma unroll
    for (int ct = 0; ct < 4; ++ct) {
        float4 l0 = *(const float4*)(lS + 0 * 64 + ct * 16 + qd * 4);
        float4 l1 = *(const float4*)(lS + 1 * 64 + ct * 16 + qd * 4);
        float4 l2 = *(const float4*)(lS + 2 * 64 + ct * 16 + qd * 4);
        float4 l3 = *(const float4*)(lS + 3 * 64 + ct * 16 + qd * 4);
#pragma unroll
        for (int r = 0; r < 4; ++r)
            flv[ct][r] = (&l0.x)[r] + (&l1.x)[r] + (&l2.x)[r] + (&l3.x)[r];
    }

    if (DIRECT) {
#pragma unroll
        for (int ct = 0; ct < 4; ++ct) {
            int rowg = b * 2048 + c0 + ct * 16 + qd * 4;
#pragma unroll
            for (int r = 0; r < 4; ++r) {
                float inv = 1.f / flv[ct][r];
#pragma unroll
                for (int dt = 0; dt < 4; ++dt)
                    out[(size_t)(rowg + r) * 256 + w * 64 + dt * 16 + ln] =
                        o[ct][dt][r] * inv;
            }
        }
    } else {
        // write unnormalized partial (64 KB + l), then race on the pair flag
        float* op = Opart + (size_t)sp * (16384 * 256);
#pragma unroll
        for (int ct = 0; ct < 4; ++ct) {
            int rowg = b * 2048 + c0 + ct * 16 + qd * 4;
#pragma unroll
            for (int r = 0; r < 4; ++r)
#pragma unroll
                for (int dt = 0; dt < 4; ++dt)
                    op[(size_t)(rowg + r) * 256 + w * 64 + dt * 16 + ln] = o[ct][dt][r];
            if (ln == 0)
                *(float4*)(lpart + sp * 16384 + rowg) =
                    make_float4(flv[ct][0], flv[ct][1], flv[ct][2], flv[ct][3]);
        }
        __threadfence();
        if (tid == 0) {
            int pair = b * 32 + (t & 31);
            who = __hip_atomic_fetch_add(&flags[pair], 1, __ATOMIC_ACQ_REL,
                                         __HIP_MEMORY_SCOPE_AGENT);
        }
        __syncthreads();
        if (who == 0) return;                // first arriver: partner combines

        // finisher: own accumulators (regs) + other half's partial -> out
        int osp = sp ^ 1;
        const float* oo = Opart + (size_t)osp * (16384 * 256);
        const float* ol = lpart + osp * 16384;
#pragma unroll
        for (int ct = 0; ct < 4; ++ct) {
            int rowg = b * 2048 + c0 + ct * 16 + qd * 4;
#pragma unroll
            for (int r = 0; r < 4; ++r) {
                float inv = 1.f / (flv[ct][r] + ol[rowg + r]);
#pragma unroll
                for (int dt = 0; dt < 4; ++dt) {
                    int col = w * 64 + dt * 16 + ln;
                    float sum = o[ct][dt][r] + oo[(size_t)(rowg + r) * 256 + col];
                    out[(size_t)(rowg + r) * 256 + col] = sum * inv;
                }
            }
        }
    }
}

extern "C" void kernel_launch(void* const* d_in, const int* in_sizes, int n_in,
                              void* d_out, int out_size, void* d_ws, size_t ws_size,
                              hipStream_t stream) {
    const float* ctx  = (const float*)d_in[0];
    const float* qry  = (const float*)d_in[1];
    const float* win  = (const float*)d_in[2];
    const float* wmem = (const float*)d_in[3];
    const int* qmask  = (const int*)d_in[4];
    float* out = (float*)d_out;

    char* ws = (char*)d_ws;
    short* Qa      = (short*)(ws);                          // 4 MB
    short* Ka      = (short*)(ws + (4u << 20));             // 4 MB
    short* VaT     = (short*)(ws + (8u << 20));             // 8 MB
    float* maskadd = (float*)(ws + (16u << 20));            // 64 KB
    int*   flags   = (int*)(ws + (16u << 20) + 65536);      // 1 KB
    float* lpart   = (float*)(ws + (16u << 20) + 131072);   // 128 KB
    float* Opart   = (float*)(ws + (18u << 20));            // NSPLIT x 16 MB

    k_pre<<<dim3(1536), 256, 0, stream>>>(ctx, qry, win, wmem, qmask,
                                          Qa, Ka, VaT, maskadd, flags);

    const size_t base = 18u << 20, part = 16u << 20;
    if (ws_size >= base + 2 * part) {
        k_attn<2, false><<<dim3(512), 256, 0, stream>>>(Qa, Ka, VaT, maskadd,
                                                        Opart, lpart, flags, out);
    } else {
        k_attn<1, true><<<dim3(256), 256, 0, stream>>>(Qa, Ka, VaT, maskadd,
                                                       Opart, lpart, flags, out);
    }
}

// Round 3
// 153.117 us; speedup vs baseline: 1.4987x; 1.4987x over previous
//
#include <hip/hip_runtime.h>
#include <math.h>

typedef short v4s __attribute__((ext_vector_type(4)));
typedef short v8s __attribute__((ext_vector_type(8)));
typedef float v4f __attribute__((ext_vector_type(4)));

#define L2E 1.4426950408889634f
#define INV_SCALE 0.08838834764831845f       // 1/sqrt(128)
#define SCL2 (INV_SCALE * L2E)               // folded scale for exp2

static __device__ __forceinline__ short f2bf(float x) {
    union { float f; unsigned u; } c; c.f = x;
    unsigned u = c.u;
    unsigned r = (u + 0x7fffu + ((u >> 16) & 1u)) >> 16;  // RNE
    return (short)r;
}

typedef __attribute__((address_space(3))) void lds_vt;
typedef __attribute__((address_space(1))) const void gl_vt;
static __device__ __forceinline__ void gload_lds16(const void* g, void* l) {
    __builtin_amdgcn_global_load_lds((gl_vt*)g, (lds_vt*)l, 16, 0, 0);
}

// ---- P0 fused: gemm+ELU role (x<512) | transpose/mask role (x>=512) -----
// gemm role: full 128-f output per 64 m rows; W staged in two k-halves in
// the same 33.8 KB LDS -> X rows read ONCE. VaT written with per-row
// chunk-XOR swizzle (g^(d&7) inside each 64-kv group) for conflict-free
// ds_read_b128 B-frags in k_attn.
__global__ __launch_bounds__(256) void k_pre(const float* __restrict__ ctx,
                                             const float* __restrict__ qry,
                                             const float* __restrict__ Win,
                                             const float* __restrict__ Wmem,
                                             const int* __restrict__ qmask,
                                             short* __restrict__ Qa,
                                             short* __restrict__ Ka,
                                             short* __restrict__ VaT,
                                             float* __restrict__ maskadd) {
    __shared__ __align__(16) char sbuf[128 * 132 * 2];   // 33792 B (union)
    int x = blockIdx.x;
    int tid = threadIdx.x;
    if (x < 512) {
        // ---------------- gemm role ----------------
        short* WtS = (short*)sbuf;                      // [128 f][132 k-pad]
        int msel = x & 255, isel = x >> 8;
        const float* X = isel ? qry : ctx;
        const float* W = isel ? Wmem : Win;
        short* Y = isel ? Ka : Qa;

        int w = tid >> 6, lane = tid & 63;
        int ln = lane & 15, qd = lane >> 4;
        int m0 = msel * 64 + w * 16;
        v4f zero = {0.f, 0.f, 0.f, 0.f};
        v4f o[8];
#pragma unroll
        for (int i = 0; i < 8; ++i) o[i] = zero;

#pragma unroll 1
        for (int kh = 0; kh < 2; ++kh) {
            if (kh) __syncthreads();                    // protect WtS reuse
            // stage W k-half: 128 f x 128 k = 16384 elems, 64/thread
#pragma unroll 8
            for (int i = 0; i < 64; ++i) {
                int id = i * 256 + tid;
                int k = id >> 7, fp = id & 127;
                WtS[fp * 132 + k] = f2bf(W[(kh * 128 + k) * 128 + fp]);
            }
            __syncthreads();
#pragma unroll
            for (int kk = 0; kk < 4; ++kk) {
                const float* xp = X + (size_t)(m0 + ln) * 256 + kh * 128 + kk * 32 + qd * 8;
                float4 x0 = *(const float4*)xp;
                float4 x1 = *(const float4*)(xp + 4);
                v8s a;
                a[0] = f2bf(x0.x); a[1] = f2bf(x0.y); a[2] = f2bf(x0.z); a[3] = f2bf(x0.w);
                a[4] = f2bf(x1.x); a[5] = f2bf(x1.y); a[6] = f2bf(x1.z); a[7] = f2bf(x1.w);
#pragma unroll
                for (int nt = 0; nt < 8; ++nt) {
                    v8s bfr = *(const v8s*)(WtS + (nt * 16 + ln) * 132 + kk * 32 + qd * 8);
                    o[nt] = __builtin_amdgcn_mfma_f32_16x16x32_bf16(a, bfr, o[nt], 0, 0, 0);
                }
            }
        }
#pragma unroll
        for (int nt = 0; nt < 8; ++nt) {
#pragma unroll
            for (int r = 0; r < 4; ++r) {
                float v = o[nt][r];
                v = v > 0.f ? v : 0.01f * (__expf(v) - 1.f);
                Y[(size_t)(m0 + qd * 4 + r) * 128 + nt * 16 + ln] = f2bf(v);
            }
        }
    } else {
        // ---------------- transpose role ----------------
        float (*tile)[65] = (float(*)[65])sbuf;         // 16640 B
        int t = x - 512;
        int q0 = (t & 31) * 64, d0 = ((t >> 5) & 3) * 64, b = t >> 7;
        int c = tid & 63;
        int r4 = tid >> 6;
#pragma unroll
        for (int i = 0; i < 16; ++i) {
            int r = r4 + i * 4;
            tile[r][c] = qry[(size_t)(b * 2048 + q0 + r) * 256 + d0 + c];
        }
        __syncthreads();
        int g = c >> 3, j = c & 7;
#pragma unroll
        for (int i = 0; i < 16; ++i) {
            int d = r4 + i * 4;                          // (d0+d)&7 == d&7
            int cs = ((g ^ (d & 7)) << 3) | j;           // chunk-XOR swizzle
            VaT[(size_t)(b * 256 + d0 + d) * 2048 + q0 + cs] = f2bf(tile[c][d]);
        }
        if (d0 == 0 && tid < 64) {
            int qq = b * 2048 + q0 + tid;
            maskadd[qq] = (qmask[qq] > 0) ? 0.f : -__builtin_inff();
        }
    }
}

// ------------- flash attention: kv-split, depth-2 counted-vmcnt pipe ------
// Grid 512 (NSPLIT=2): 8 b x 32 c-tiles x 2 kv-halves, 2 blocks/CU.
// Pipeline (steady state, 26 VMEM in flight before the wait):
//   issue order: ... stage(it)[8] | kf(it)[5] | stage(it+1)[8] | kf(it+1)[5]
//   one s_waitcnt vmcnt(13)/step retires exactly stage(it)+kf(it) (V tile in
//   LDS + K regs ready), keeps stage(it+1)+kf(it+1) flying across BOTH
//   barriers. stage(it+2 -> buf[it&1]) is issued at end of step it, right
//   after that buffer's wave-private PV reads drain -> full-step window.
// V: [buf][d][64kv] wave-private d-quarters (no barrier needed for V).
// P: single buffer, chunk-XOR swizzled; 2 raw s_barriers/step (visibility,
// WAR). The vmcnt wait is the ONLY guard for DMA->ds_read (compiler can't
// see that dep).
template<int NSPLIT, bool DIRECT>
__global__ __launch_bounds__(256, 2) void k_attn(const short* __restrict__ Qa,
                                                 const short* __restrict__ Ka,
                                                 const short* __restrict__ VaT,
                                                 const float* __restrict__ maskadd,
                                                 float* __restrict__ Opart,
                                                 float* __restrict__ lpart,
                                                 float* __restrict__ out) {
    __shared__ __align__(16) short VaS[2][256 * 64];    // 64 KB swizzled V
    __shared__ __align__(16) short PS[64 * 64];         // 8 KB swizzled P
    __shared__ float lS[4 * 64];                        // 1 KB

    const int STEPS = 32 / NSPLIT;
    int blk = blockIdx.x;
    int b = blk & 7;
    int t = blk >> 3;
    int c0 = (t & 31) * 64;
    int sp = t >> 5;
    int kv0 = sp * (2048 / NSPLIT);

    int tid = threadIdx.x;
    int w = tid >> 6, lane = tid & 63, ln = lane & 15, qd = lane >> 4;

    const short* qbase = Qa + (size_t)(b * 2048) * 128;
    const short* kbase = Ka + (size_t)(b * 2048 + kv0 + w * 16 + ln) * 128 + qd * 8;
    const short* vbase = VaT + (size_t)(b * 256) * 2048;
    const float* mbase = maskadd + b * 2048 + kv0 + w * 16 + qd * 4;

    // Q fragments for all 4 c-tiles (B-operand layout), resident
    v8s qf[4][4];
#pragma unroll
    for (int ct = 0; ct < 4; ++ct) {
        const short* qp = qbase + (size_t)(c0 + ct * 16 + ln) * 128 + qd * 8;
#pragma unroll
        for (int kk = 0; kk < 4; ++kk) qf[ct][kk] = *(const v8s*)(qp + kk * 32);
    }

    v4f zero = {0.f, 0.f, 0.f, 0.f};
    v4f o[4][4];                            // [ct][dt]
#pragma unroll
    for (int i = 0; i < 4; ++i)
#pragma unroll
        for (int j = 0; j < 4; ++j) o[i][j] = zero;
    float lacc[4] = {0.f, 0.f, 0.f, 0.f};

    // stage own d-quarter of V tile for kv window q0s into buf (wave-private)
    auto stageV = [&](int q0s, int buf) {
        short* base = &VaS[buf][0] + w * 4096;   // rows w*64..+63
#pragma unroll
        for (int j = 0; j < 8; ++j) {
            int U = (w * 8 + j) * 64 + lane;     // 16B unit index
            int d = U >> 3, cc = U & 7;
            gload_lds16(vbase + (size_t)d * 2048 + q0s + cc * 8,
                        base + j * 512);
        }
    };

    // ---- prologue: stage0 | kf0 | stage1 (order pinned for in-order
    // vmcnt retirement arithmetic) ----
    v8s kfA[4], kfB[4];
    float4 mkA, mkB;
    stageV(kv0, 0);
    asm volatile("" ::: "memory");
#pragma unroll
    for (int kk = 0; kk < 4; ++kk) kfA[kk] = *(const v8s*)(kbase + kk * 32);
    mkA = *(const float4*)(mbase);
    asm volatile("" ::: "memory");
    stageV(kv0 + 64, 1);

#define ATT_STEP(IT, KFC, MKC, KFN, MKN) do {                                  \
    int q0 = kv0 + (IT) * 64;                                                  \
    int itn = ((IT) + 1) & (STEPS - 1);                                        \
    int itn2 = ((IT) + 2) & (STEPS - 1);                                       \
    {   /* prefetch NEXT step's K frags + mask into regs (5 VMEM) */           \
        const short* kp = kbase + (size_t)itn * 8192;                          \
        _Pragma("unroll")                                                      \
        for (int kk = 0; kk < 4; ++kk) KFN[kk] = *(const v8s*)(kp + kk * 32);  \
        MKN = *(const float4*)(mbase + itn * 64);                              \
    }                                                                          \
    /* retire stage(IT)+kf(IT); keep stage(IT+1)+kf(IT+1) = 13 in flight */    \
    asm volatile("s_waitcnt vmcnt(13)" ::: "memory");                          \
    int kvb = q0 + w * 16 + qd * 4;                                            \
    _Pragma("unroll")                                                          \
    for (int ct = 0; ct < 4; ++ct) {                                           \
        v4f s = zero;                                                          \
        _Pragma("unroll")                                                      \
        for (int kk = 0; kk < 4; ++kk)                                         \
            s = __builtin_amdgcn_mfma_f32_16x16x32_bf16(KFC[kk], qf[ct][kk],   \
                                                        s, 0, 0, 0);           \
        int cg = c0 + ct * 16 + ln;                                            \
        v4s pw;                                                                \
        float ls = 0.f;                                                        \
        _Pragma("unroll")                                                      \
        for (int r = 0; r < 4; ++r) {                                          \
            float v = s[r] * SCL2 + (&MKC.x)[r];                               \
            if (kvb + r == cg) v = -__builtin_inff();                          \
            float p = exp2f(v);                                                \
            ls += p;                                                           \
            pw[r] = f2bf(p);                                                   \
        }                                                                      \
        lacc[ct] += ls;                                                        \
        int hs = ((w * 2 + (qd >> 1)) ^ (ln & 7));                             \
        *(v4s*)(PS + (ct * 16 + ln) * 64 + hs * 8 + (qd & 1) * 4) = pw;        \
    }                                                                          \
    asm volatile("s_waitcnt lgkmcnt(0)" ::: "memory");                         \
    __builtin_amdgcn_s_barrier();           /* P visible */                    \
    const short* vs = &VaS[(IT) & 1][0];                                       \
    __builtin_amdgcn_s_setprio(1);                                             \
    _Pragma("unroll")                                                          \
    for (int kk2 = 0; kk2 < 2; ++kk2) {                                        \
        v8s pf[4], vf[4];                                                      \
        _Pragma("unroll")                                                      \
        for (int ct = 0; ct < 4; ++ct)                                         \
            pf[ct] = *(const v8s*)(PS + (ct * 16 + ln) * 64 +                  \
                                   (((kk2 * 4 + qd) ^ (ln & 7)) << 3));        \
        _Pragma("unroll")                                                      \
        for (int dt = 0; dt < 4; ++dt) {                                       \
            int d = w * 64 + dt * 16 + ln;                                     \
            vf[dt] = *(const v8s*)(vs + d * 64 +                               \
                                   (((kk2 * 4 + qd) ^ (ln & 7)) << 3));        \
        }                                                                      \
        _Pragma("unroll")                                                      \
        for (int ct = 0; ct < 4; ++ct)                                         \
            _Pragma("unroll")                                                  \
            for (int dt = 0; dt < 4; ++dt)                                     \
                o[ct][dt] = __builtin_amdgcn_mfma_f32_16x16x32_bf16(           \
                    pf[ct], vf[dt], o[ct][dt], 0, 0, 0);                       \
    }                                                                          \
    __builtin_amdgcn_s_setprio(0);                                             \
    /* own P+V ds_reads drained -> safe to DMA-overwrite buf[(IT)&1] */        \
    asm volatile("s_waitcnt lgkmcnt(0)" ::: "memory");                         \
    stageV(kv0 + itn2 * 64, (IT) & 1);                                         \
    __builtin_amdgcn_s_barrier();           /* protect P for next write */     \
} while (0)

#pragma unroll 1
    for (int it2 = 0; it2 < STEPS; it2 += 2) {
        ATT_STEP(it2, kfA, mkA, kfB, mkB);
        ATT_STEP(it2 + 1, kfB, mkB, kfA, mkA);
    }
#undef ATT_STEP

    // ---- l: reduce over qd in-wave, over waves via LDS ----
    __syncthreads();                         // also drains trailing DMA
#pragma unroll
    for (int ct = 0; ct < 4; ++ct) {
        float v = lacc[ct];
        v += __shfl_xor(v, 16);
        v += __shfl_xor(v, 32);
        if (qd == 0) lS[w * 64 + ct * 16 + ln] = v;
    }
    __syncthreads();

#pragma unroll
    for (int ct = 0; ct < 4; ++ct) {
        float4 l0 = *(const float4*)(lS + 0 * 64 + ct * 16 + qd * 4);
        float4 l1 = *(const float4*)(lS + 1 * 64 + ct * 16 + qd * 4);
        float4 l2 = *(const float4*)(lS + 2 * 64 + ct * 16 + qd * 4);
        float4 l3 = *(const float4*)(lS + 3 * 64 + ct * 16 + qd * 4);
        float lv[4];
#pragma unroll
        for (int r = 0; r < 4; ++r)
            lv[r] = (&l0.x)[r] + (&l1.x)[r] + (&l2.x)[r] + (&l3.x)[r];
        int rowg = b * 2048 + c0 + ct * 16 + qd * 4;
        if (DIRECT) {
#pragma unroll
            for (int r = 0; r < 4; ++r) {
                float inv = 1.f / lv[r];
#pragma unroll
                for (int dt = 0; dt < 4; ++dt)
                    out[(size_t)(rowg + r) * 256 + w * 64 + dt * 16 + ln] =
                        o[ct][dt][r] * inv;
            }
        } else {
            float* op = Opart + (size_t)sp * (16384 * 256);
#pragma unroll
            for (int r = 0; r < 4; ++r)
#pragma unroll
                for (int dt = 0; dt < 4; ++dt)
                    op[(size_t)(rowg + r) * 256 + w * 64 + dt * 16 + ln] = o[ct][dt][r];
            if (ln == 0)
                *(float4*)(lpart + sp * 16384 + rowg) =
                    make_float4(lv[0], lv[1], lv[2], lv[3]);
        }
    }
}

// ---------------- combine partials across NSPLIT kv-splits ----------------
template<int NSPLIT>
__global__ __launch_bounds__(256) void k_combine(const float* __restrict__ Opart,
                                                 const float* __restrict__ lpart,
                                                 float* __restrict__ out) {
    int idx = blockIdx.x * 256 + threadIdx.x;    // 16384 rows x 64 float4s
    int row = idx >> 6, d4 = (idx & 63) * 4;
    float L = 0.f;
    float4 acc = {0.f, 0.f, 0.f, 0.f};
#pragma unroll
    for (int s = 0; s < NSPLIT; ++s) {
        L += lpart[s * 16384 + row];
        float4 v = *(const float4*)(Opart + (size_t)s * (16384 * 256) + (size_t)row * 256 + d4);
        acc.x += v.x; acc.y += v.y; acc.z += v.z; acc.w += v.w;
    }
    float inv = 1.f / L;
    float4 res = {acc.x * inv, acc.y * inv, acc.z * inv, acc.w * inv};
    *(float4*)(out + (size_t)row * 256 + d4) = res;
}

extern "C" void kernel_launch(void* const* d_in, const int* in_sizes, int n_in,
                              void* d_out, int out_size, void* d_ws, size_t ws_size,
                              hipStream_t stream) {
    const float* ctx  = (const float*)d_in[0];
    const float* qry  = (const float*)d_in[1];
    const float* win  = (const float*)d_in[2];
    const float* wmem = (const float*)d_in[3];
    const int* qmask  = (const int*)d_in[4];
    float* out = (float*)d_out;

    char* ws = (char*)d_ws;
    short* Qa      = (short*)(ws);                          // 4 MB
    short* Ka      = (short*)(ws + (4u << 20));             // 4 MB
    short* VaT     = (short*)(ws + (8u << 20));             // 8 MB
    float* maskadd = (float*)(ws + (16u << 20));            // 64 KB
    float* lpart   = (float*)(ws + (16u << 20) + 131072);   // up to 256 KB
    float* Opart   = (float*)(ws + (18u << 20));            // NSPLIT x 16 MB

    k_pre<<<dim3(1536), 256, 0, stream>>>(ctx, qry, win, wmem, qmask,
                                          Qa, Ka, VaT, maskadd);

    const size_t base = 18u << 20, part = 16u << 20;
    if (ws_size >= base + 2 * part) {
        k_attn<2, false><<<dim3(512), 256, 0, stream>>>(Qa, Ka, VaT, maskadd,
                                                        Opart, lpart, out);
        k_combine<2><<<dim3(4096), 256, 0, stream>>>(Opart, lpart, out);
    } else {
        k_attn<1, true><<<dim3(256), 256, 0, stream>>>(Qa, Ka, VaT, maskadd,
                                                       Opart, lpart, out);
    }
}

// Round 5
// 151.103 us; speedup vs baseline: 1.5187x; 1.0133x over previous
//
#include <hip/hip_runtime.h>
#include <math.h>

typedef short v4s __attribute__((ext_vector_type(4)));
typedef short v8s __attribute__((ext_vector_type(8)));
typedef float v4f __attribute__((ext_vector_type(4)));

#define L2E 1.4426950408889634f
#define INV_SCALE 0.08838834764831845f       // 1/sqrt(128)
#define SCL2 (INV_SCALE * L2E)               // folded scale for exp2

static __device__ __forceinline__ short f2bf(float x) {
    union { float f; unsigned u; } c; c.f = x;
    unsigned u = c.u;
    unsigned r = (u + 0x7fffu + ((u >> 16) & 1u)) >> 16;  // RNE
    return (short)r;
}

typedef __attribute__((address_space(3))) void lds_vt;
typedef __attribute__((address_space(1))) const void gl_vt;
static __device__ __forceinline__ void gload_lds16(const void* g, void* l) {
    __builtin_amdgcn_global_load_lds((gl_vt*)g, (lds_vt*)l, 16, 0, 0);
}

// ---- P0 fused: gemm+ELU role (x<512) | transpose/mask role (x>=512) -----
// gemm role: full 128-f output per 64 m rows; W staged in two k-halves in
// the same 33.8 KB LDS -> X rows read ONCE. VaT written with per-row
// chunk-XOR swizzle (g^(d&7) inside each 64-kv group) for conflict-free
// ds_read_b128 B-frags in k_attn.
__global__ __launch_bounds__(256) void k_pre(const float* __restrict__ ctx,
                                             const float* __restrict__ qry,
                                             const float* __restrict__ Win,
                                             const float* __restrict__ Wmem,
                                             const int* __restrict__ qmask,
                                             short* __restrict__ Qa,
                                             short* __restrict__ Ka,
                                             short* __restrict__ VaT,
                                             float* __restrict__ maskadd) {
    __shared__ __align__(16) char sbuf[128 * 132 * 2];   // 33792 B (union)
    int x = blockIdx.x;
    int tid = threadIdx.x;
    if (x < 512) {
        // ---------------- gemm role ----------------
        short* WtS = (short*)sbuf;                      // [128 f][132 k-pad]
        int msel = x & 255, isel = x >> 8;
        const float* X = isel ? qry : ctx;
        const float* W = isel ? Wmem : Win;
        short* Y = isel ? Ka : Qa;

        int w = tid >> 6, lane = tid & 63;
        int ln = lane & 15, qd = lane >> 4;
        int m0 = msel * 64 + w * 16;
        v4f zero = {0.f, 0.f, 0.f, 0.f};
        v4f o[8];
#pragma unroll
        for (int i = 0; i < 8; ++i) o[i] = zero;

#pragma unroll 1
        for (int kh = 0; kh < 2; ++kh) {
            if (kh) __syncthreads();                    // protect WtS reuse
            // stage W k-half: 128 f x 128 k = 16384 elems, 64/thread
#pragma unroll 8
            for (int i = 0; i < 64; ++i) {
                int id = i * 256 + tid;
                int k = id >> 7, fp = id & 127;
                WtS[fp * 132 + k] = f2bf(W[(kh * 128 + k) * 128 + fp]);
            }
            __syncthreads();
#pragma unroll
            for (int kk = 0; kk < 4; ++kk) {
                const float* xp = X + (size_t)(m0 + ln) * 256 + kh * 128 + kk * 32 + qd * 8;
                float4 x0 = *(const float4*)xp;
                float4 x1 = *(const float4*)(xp + 4);
                v8s a;
                a[0] = f2bf(x0.x); a[1] = f2bf(x0.y); a[2] = f2bf(x0.z); a[3] = f2bf(x0.w);
                a[4] = f2bf(x1.x); a[5] = f2bf(x1.y); a[6] = f2bf(x1.z); a[7] = f2bf(x1.w);
#pragma unroll
                for (int nt = 0; nt < 8; ++nt) {
                    v8s bfr = *(const v8s*)(WtS + (nt * 16 + ln) * 132 + kk * 32 + qd * 8);
                    o[nt] = __builtin_amdgcn_mfma_f32_16x16x32_bf16(a, bfr, o[nt], 0, 0, 0);
                }
            }
        }
#pragma unroll
        for (int nt = 0; nt < 8; ++nt) {
#pragma unroll
            for (int r = 0; r < 4; ++r) {
                float v = o[nt][r];
                v = v > 0.f ? v : 0.01f * (__expf(v) - 1.f);
                Y[(size_t)(m0 + qd * 4 + r) * 128 + nt * 16 + ln] = f2bf(v);
            }
        }
    } else {
        // ---------------- transpose role ----------------
        float (*tile)[65] = (float(*)[65])sbuf;         // 16640 B
        int t = x - 512;
        int q0 = (t & 31) * 64, d0 = ((t >> 5) & 3) * 64, b = t >> 7;
        int c = tid & 63;
        int r4 = tid >> 6;
#pragma unroll
        for (int i = 0; i < 16; ++i) {
            int r = r4 + i * 4;
            tile[r][c] = qry[(size_t)(b * 2048 + q0 + r) * 256 + d0 + c];
        }
        __syncthreads();
        int g = c >> 3, j = c & 7;
#pragma unroll
        for (int i = 0; i < 16; ++i) {
            int d = r4 + i * 4;                          // (d0+d)&7 == d&7
            int cs = ((g ^ (d & 7)) << 3) | j;           // chunk-XOR swizzle
            VaT[(size_t)(b * 256 + d0 + d) * 2048 + q0 + cs] = f2bf(tile[c][d]);
        }
        if (d0 == 0 && tid < 64) {
            int qq = b * 2048 + q0 + tid;
            maskadd[qq] = (qmask[qq] > 0) ? 0.f : -__builtin_inff();
        }
    }
}

// ------------- flash attention: IN-BLOCK kv-split, direct out -------------
// 256 blocks x 512 thr (8 waves = 2 groups of 4). Group g owns kv-half
// [g*1024, g*1024+1024): 16 steps of 64 kv, R3's depth-2 counted-vmcnt
// schedule per group (K/mask reg-prefetch 1 step ahead; V wave-private
// d-quarter dbuf via async global_load_lds; P per-group LDS chunk-XOR).
// s_barrier syncs all 8 waves (both groups run identical instr streams ->
// bounded skew). End: group 1 dumps unnormalized O to LDS, group 0 merges
// regs + LDS, normalizes, writes out. NO partials in HBM, NO combine kernel.
__global__ __launch_bounds__(512, 2) void k_attn(const short* __restrict__ Qa,
                                                 const short* __restrict__ Ka,
                                                 const short* __restrict__ VaT,
                                                 const float* __restrict__ maskadd,
                                                 float* __restrict__ out) {
    __shared__ __align__(16) short VaS[2][2][256 * 64];  // 128 KB [grp][buf]
    __shared__ __align__(16) short PS[2][64 * 64];       // 16 KB [grp] swizzled
    __shared__ float lS[8 * 64];                         // 2 KB

    const int STEPS = 16;
    int blk = blockIdx.x;
    int b = blk & 7;
    int c0 = (blk >> 3) * 64;

    int tid = threadIdx.x;
    int w = tid >> 6, lane = tid & 63, ln = lane & 15, qd = lane >> 4;
    int g = w >> 2, wl = w & 3;              // group, wave-in-group
    int kv0 = g * 1024;

    const short* qbase = Qa + (size_t)(b * 2048) * 128;
    const short* kbase = Ka + (size_t)(b * 2048 + kv0 + wl * 16 + ln) * 128 + qd * 8;
    const short* vbase = VaT + (size_t)(b * 256) * 2048;
    const float* mbase = maskadd + b * 2048 + kv0 + wl * 16 + qd * 4;

    // Q fragments for all 4 c-tiles (B-operand layout), resident
    v8s qf[4][4];
#pragma unroll
    for (int ct = 0; ct < 4; ++ct) {
        const short* qp = qbase + (size_t)(c0 + ct * 16 + ln) * 128 + qd * 8;
#pragma unroll
        for (int kk = 0; kk < 4; ++kk) qf[ct][kk] = *(const v8s*)(qp + kk * 32);
    }

    v4f zero = {0.f, 0.f, 0.f, 0.f};
    v4f o[4][4];                            // [ct][dt]
#pragma unroll
    for (int i = 0; i < 4; ++i)
#pragma unroll
        for (int j = 0; j < 4; ++j) o[i][j] = zero;
    float lacc[4] = {0.f, 0.f, 0.f, 0.f};

    // stage own d-quarter of V tile for kv window q0s into buf (wave-private)
    auto stageV = [&](int q0s, int buf) {
        short* base = &VaS[g][buf][0] + wl * 4096;   // rows wl*64..+63
#pragma unroll
        for (int j = 0; j < 8; ++j) {
            int U = (wl * 8 + j) * 64 + lane;        // 16B unit index
            int d = U >> 3, cc = U & 7;
            gload_lds16(vbase + (size_t)d * 2048 + q0s + cc * 8,
                        base + j * 512);
        }
    };

    // ---- prologue: stage0 | kf0 | stage1 (order pinned for in-order
    // vmcnt retirement arithmetic) ----
    v8s kfA[4], kfB[4];
    float4 mkA, mkB;
    stageV(kv0, 0);
    asm volatile("" ::: "memory");
#pragma unroll
    for (int kk = 0; kk < 4; ++kk) kfA[kk] = *(const v8s*)(kbase + kk * 32);
    mkA = *(const float4*)(mbase);
    asm volatile("" ::: "memory");
    stageV(kv0 + 64, 1);

#define ATT_STEP(IT, KFC, MKC, KFN, MKN) do {                                  \
    int q0 = kv0 + (IT) * 64;                                                  \
    int itn = ((IT) + 1) & (STEPS - 1);                                        \
    int itn2 = ((IT) + 2) & (STEPS - 1);                                       \
    {   /* prefetch NEXT step's K frags + mask into regs (5 VMEM) */           \
        const short* kp = kbase + (size_t)itn * 8192;                          \
        _Pragma("unroll")                                                      \
        for (int kk = 0; kk < 4; ++kk) KFN[kk] = *(const v8s*)(kp + kk * 32);  \
        MKN = *(const float4*)(mbase + itn * 64);                              \
    }                                                                          \
    /* retire stage(IT)+kf(IT); keep stage(IT+1)+kf(IT+1) = 13 in flight */    \
    asm volatile("s_waitcnt vmcnt(13)" ::: "memory");                          \
    int kvb = q0 + wl * 16 + qd * 4;                                           \
    _Pragma("unroll")                                                          \
    for (int ct = 0; ct < 4; ++ct) {                                           \
        v4f s = zero;                                                          \
        _Pragma("unroll")                                                      \
        for (int kk = 0; kk < 4; ++kk)                                         \
            s = __builtin_amdgcn_mfma_f32_16x16x32_bf16(KFC[kk], qf[ct][kk],   \
                                                        s, 0, 0, 0);           \
        int cg = c0 + ct * 16 + ln;                                            \
        v4s pw;                                                                \
        float ls = 0.f;                                                        \
        _Pragma("unroll")                                                      \
        for (int r = 0; r < 4; ++r) {                                          \
            float v = s[r] * SCL2 + (&MKC.x)[r];                               \
            if (kvb + r == cg) v = -__builtin_inff();                          \
            float p = exp2f(v);                                                \
            ls += p;                                                           \
            pw[r] = f2bf(p);                                                   \
        }                                                                      \
        lacc[ct] += ls;                                                        \
        int hs = ((wl * 2 + (qd >> 1)) ^ (ln & 7));                            \
        *(v4s*)(&PS[g][0] + (ct * 16 + ln) * 64 + hs * 8 + (qd & 1) * 4) = pw; \
    }                                                                          \
    asm volatile("s_waitcnt lgkmcnt(0)" ::: "memory");                         \
    __builtin_amdgcn_s_barrier();           /* P visible */                    \
    const short* vs = &VaS[g][(IT) & 1][0];                                    \
    __builtin_amdgcn_s_setprio(1);                                             \
    _Pragma("unroll")                                                          \
    for (int kk2 = 0; kk2 < 2; ++kk2) {                                        \
        v8s pf[4], vf[4];                                                      \
        _Pragma("unroll")                                                      \
        for (int ct = 0; ct < 4; ++ct)                                         \
            pf[ct] = *(const v8s*)(&PS[g][0] + (ct * 16 + ln) * 64 +           \
                                   (((kk2 * 4 + qd) ^ (ln & 7)) << 3));        \
        _Pragma("unroll")                                                      \
        for (int dt = 0; dt < 4; ++dt) {                                       \
            int d = wl * 64 + dt * 16 + ln;                                    \
            vf[dt] = *(const v8s*)(vs + d * 64 +                               \
                                   (((kk2 * 4 + qd) ^ (ln & 7)) << 3));        \
        }                                                                      \
        _Pragma("unroll")                                                      \
        for (int ct = 0; ct < 4; ++ct)                                         \
            _Pragma("unroll")                                                  \
            for (int dt = 0; dt < 4; ++dt)                                     \
                o[ct][dt] = __builtin_amdgcn_mfma_f32_16x16x32_bf16(           \
                    pf[ct], vf[dt], o[ct][dt], 0, 0, 0);                       \
    }                                                                          \
    __builtin_amdgcn_s_setprio(0);                                             \
    /* own P+V ds_reads drained -> safe to DMA-overwrite buf[(IT)&1] */        \
    asm volatile("s_waitcnt lgkmcnt(0)" ::: "memory");                         \
    stageV(kv0 + itn2 * 64, (IT) & 1);                                         \
    __builtin_amdgcn_s_barrier();           /* protect P for next write */     \
} while (0)

#pragma unroll 1
    for (int it2 = 0; it2 < STEPS; it2 += 2) {
        ATT_STEP(it2, kfA, mkA, kfB, mkB);
        ATT_STEP(it2 + 1, kfB, mkB, kfA, mkA);
    }
#undef ATT_STEP

    // ---- epilogue: drain trailing DMAs, then combine the two kv-halves ----
    asm volatile("s_waitcnt vmcnt(0)" ::: "memory");
    __syncthreads();

    // l: reduce over qd in-wave, publish per-wave sums
#pragma unroll
    for (int ct = 0; ct < 4; ++ct) {
        float v = lacc[ct];
        v += __shfl_xor(v, 16);
        v += __shfl_xor(v, 32);
        if (qd == 0) lS[w * 64 + ct * 16 + ln] = v;
    }

    // group 1 dumps unnormalized O into LDS (VaS reused; stride 260 pads
    // the 256-f32 row to kill the 4-way qd bank alias)
    float* OS = (float*)&VaS[0][0][0];       // [64 c][260 d-pad] f32, 66.6 KB
    if (g == 1) {
#pragma unroll
        for (int ct = 0; ct < 4; ++ct)
#pragma unroll
            for (int r = 0; r < 4; ++r)
#pragma unroll
                for (int dt = 0; dt < 4; ++dt)
                    OS[(ct * 16 + qd * 4 + r) * 260 + wl * 64 + dt * 16 + ln] =
                        o[ct][dt][r];
    }
    __syncthreads();

    if (g == 0) {
#pragma unroll
        for (int ct = 0; ct < 4; ++ct) {
            float lv[4];
#pragma unroll
            for (int r = 0; r < 4; ++r) {
                float s = 0.f;
#pragma unroll
                for (int wv = 0; wv < 8; ++wv)
                    s += lS[wv * 64 + ct * 16 + qd * 4 + r];
                lv[r] = s;
            }
            int rowg = b * 2048 + c0 + ct * 16 + qd * 4;
#pragma unroll
            for (int r = 0; r < 4; ++r) {
                float inv = 1.f / lv[r];
#pragma unroll
                for (int dt = 0; dt < 4; ++dt) {
                    int col = wl * 64 + dt * 16 + ln;
                    float sum = o[ct][dt][r] +
                                OS[(ct * 16 + qd * 4 + r) * 260 + col];
                    out[(size_t)(rowg + r) * 256 + col] = sum * inv;
                }
            }
        }
    }
}

extern "C" void kernel_launch(void* const* d_in, const int* in_sizes, int n_in,
                              void* d_out, int out_size, void* d_ws, size_t ws_size,
                              hipStream_t stream) {
    const float* ctx  = (const float*)d_in[0];
    const float* qry  = (const float*)d_in[1];
    const float* win  = (const float*)d_in[2];
    const float* wmem = (const float*)d_in[3];
    const int* qmask  = (const int*)d_in[4];
    float* out = (float*)d_out;

    char* ws = (char*)d_ws;
    short* Qa      = (short*)(ws);                          // 4 MB
    short* Ka      = (short*)(ws + (4u << 20));             // 4 MB
    short* VaT     = (short*)(ws + (8u << 20));             // 8 MB
    float* maskadd = (float*)(ws + (16u << 20));            // 64 KB

    k_pre<<<dim3(1536), 256, 0, stream>>>(ctx, qry, win, wmem, qmask,
                                          Qa, Ka, VaT, maskadd);
    k_attn<<<dim3(256), 512, 0, stream>>>(Qa, Ka, VaT, maskadd, out);
}